// Round 8
// baseline (391.387 us; speedup 1.0000x reference)
//
#include <hip/hip_runtime.h>

// Problem constants (match reference)
#define N_NODES  20000
#define N_EDGES  320000
#define N_CAND   200000
#define IN_DIM   7
#define H1C1     256         // 4 heads * 64
#define C2       32
#define NEG_SLOPE 0.2f

#define NBLK   512
#define NTHR   256
#define NT     (NBLK * NTHR)   // 131072 threads
#define NWAVES (NT / 64)       // 2048 waves

struct Params {
    const float* x; const int* ei; const int* cand;
    const float* W1; const float* a_src1; const float* a_dst1; const float* b1;
    const float* W2; const float* a_src2; const float* a_dst2; const float* b2;
    const float* Ws; const float* bs;
    float* out;
    // workspace
    float* xpad; float* n2; float* als1; float* ald1;
    float* uu; float* ww; float* q;
    int* deg;   // [0..N-1] degree, [N] scan base counter, [N+1] barrier counter
    int* off; int* cur; int* csr;
};

__device__ __forceinline__ float leaky(float e) {
    return (e > 0.f) ? e : NEG_SLOPE * e;
}

// Persistent-kernel grid barrier: monotonic counter, block-leader spin.
// Release/acquire via __threadfence (agent scope -> L2 wb/inv on gfx950).
// Bounded spin: worst case (co-residency broken) -> wrong answer, not a hang.
__device__ __forceinline__ void gbar(int* cnt, int target) {
    __syncthreads();
    if (threadIdx.x == 0) {
        __threadfence();                 // release: flush this XCD's dirty L2
        atomicAdd(cnt, 1);
        int spins = 0;
        while (atomicAdd(cnt, 0) < target) {
            __builtin_amdgcn_s_sleep(8);
            if (++spins > (1 << 22)) break;   // ~1-2 s safety valve
        }
        __threadfence();                 // acquire: invalidate stale lines
    }
    __syncthreads();
}

__global__ __launch_bounds__(NTHR, 4) void fused_kernel(Params P) {
    const int tid  = blockIdx.x * NTHR + threadIdx.x;
    const int lane = threadIdx.x & 63;
    const int wgl  = tid >> 6;
    int* bar = P.deg + N_NODES + 1;

    // ---------------- phase 1: degree histogram + alpha1/xpad + q -------------
    {
        const int4* d4 = (const int4*)(P.ei + N_EDGES);
        for (int i = tid; i < N_EDGES / 4; i += NT) {
            int4 d = d4[i];
            atomicAdd(&P.deg[d.x], 1); atomicAdd(&P.deg[d.y], 1);
            atomicAdd(&P.deg[d.z], 1); atomicAdd(&P.deg[d.w], 1);
        }
        // p1[sd][k][h] = sum_c W1[k, h*64+c] * a_{src/dst}1[h,c]  (per-block LDS)
        __shared__ float p1s[56];
        if (threadIdx.x < 56) {
            int sd = threadIdx.x / 28, rem = threadIdx.x % 28, k = rem >> 2, h = rem & 3;
            const float* a = sd ? P.a_dst1 : P.a_src1;
            float sum = 0.f;
            for (int c = 0; c < 64; ++c)
                sum += P.W1[k * H1C1 + h * 64 + c] * a[h * 64 + c];
            p1s[threadIdx.x] = sum;
        }
        __syncthreads();
        for (int v = tid; v < N_NODES; v += NT) {
            float xs[IN_DIM];
#pragma unroll
            for (int k = 0; k < IN_DIM; ++k) xs[k] = P.x[v * IN_DIM + k];
            float4 s = {0.f,0.f,0.f,0.f}, d = {0.f,0.f,0.f,0.f};
#pragma unroll
            for (int k = 0; k < IN_DIM; ++k) {
                float4 ps = *(const float4*)&p1s[k * 4];
                float4 pd = *(const float4*)&p1s[28 + k * 4];
                s.x += xs[k]*ps.x; s.y += xs[k]*ps.y; s.z += xs[k]*ps.z; s.w += xs[k]*ps.w;
                d.x += xs[k]*pd.x; d.y += xs[k]*pd.y; d.z += xs[k]*pd.z; d.w += xs[k]*pd.w;
            }
            *(float4*)&P.als1[v * 4] = s;
            *(float4*)&P.ald1[v * 4] = d;
            float4 xa = {xs[0], xs[1], xs[2], xs[3]};
            float4 xb = {xs[4], xs[5], xs[6], 1.0f};   // slot 7 = 1 folds z into acc
            *(float4*)&P.xpad[v * 8]     = xa;
            *(float4*)&P.xpad[v * 8 + 4] = xb;
        }
        if (blockIdx.x == 0) {   // q[r*256+i] = sum_c W2[i*32+c]*avec_r[c]
            const int t = threadIdx.x;
#pragma unroll
            for (int r = 0; r < 4; ++r) {
                const float* av = (r == 0) ? P.a_src2 : (r == 1) ? P.a_dst2
                                  : (r == 2) ? P.Ws : (P.Ws + C2);
                float s = 0.f;
#pragma unroll 8
                for (int c = 0; c < C2; ++c) s += P.W2[t * C2 + c] * av[c];
                P.q[r * 256 + t] = s;
            }
            if (t == 0) {
                float cu = 0.f, cw = 0.f;
                for (int c = 0; c < C2; ++c) { cu += P.b2[c]*P.Ws[c]; cw += P.b2[c]*P.Ws[C2+c]; }
                P.q[1024] = cu; P.q[1025] = cw;
            }
        }
    }
    gbar(bar, NBLK * 1);

    // ---------------- phase 2: offsets via wave scan + atomic base ------------
    if (wgl * 64 < N_NODES) {
        const int v = wgl * 64 + lane;
        const int val = (v < N_NODES) ? P.deg[v] : 0;   // csr holds real edges only
        int incl = val;
#pragma unroll
        for (int d = 1; d < 64; d <<= 1) {
            int n = __shfl_up(incl, d);
            if (lane >= d) incl += n;
        }
        const int total = __shfl(incl, 63);
        int base = 0;
        if (lane == 63) base = atomicAdd(&P.deg[N_NODES], total);
        base = __shfl(base, 63);
        if (v < N_NODES) {
            P.off[v] = base + incl - val;
            P.cur[v] = base + incl - val;
        }
    }
    gbar(bar, NBLK * 2);

    // ---------------- phase 3: scatter real edges into CSR --------------------
    {
        const int4* s4p = (const int4*)P.ei;
        const int4* d4p = (const int4*)(P.ei + N_EDGES);
        for (int i = tid; i < N_EDGES / 4; i += NT) {
            int4 s4 = s4p[i];
            int4 d4 = d4p[i];
            P.csr[atomicAdd(&P.cur[d4.x], 1)] = s4.x;
            P.csr[atomicAdd(&P.cur[d4.y], 1)] = s4.y;
            P.csr[atomicAdd(&P.cur[d4.z], 1)] = s4.z;
            P.csr[atomicAdd(&P.cur[d4.w], 1)] = s4.w;
        }
    }
    gbar(bar, NBLK * 3);

    // ---------------- phase 4: agg1 (head-per-lane-class, no-max softmax) -----
    {
        const int head = lane >> 4;          // 0..3
        const int slot = lane & 15;          // 0..15
        for (int v = wgl; v < N_NODES; v += NWAVES) {
            const int start = P.off[v];
            const int dreal = P.deg[v];
            const int dtot  = dreal + 1;     // + implicit self-loop
            const float ad = P.ald1[v * 4 + head];

            float acc[8] = {0.f,0.f,0.f,0.f,0.f,0.f,0.f,0.f};

            for (int b0 = 0; b0 < dtot; b0 += 32) {
                const int j0 = b0 + slot, j1 = b0 + slot + 16;
                const bool a0 = j0 < dtot, a1 = j1 < dtot;
                const int s0 = (j0 < dreal) ? P.csr[start + j0] : v;
                const int s1 = (j1 < dreal) ? P.csr[start + j1] : v;
                float e0 = leaky(P.als1[s0 * 4 + head] + ad); if (!a0) e0 = -1e30f;
                float e1 = leaky(P.als1[s1 * 4 + head] + ad); if (!a1) e1 = -1e30f;
                const float w0 = __expf(e0);   // inactive -> 0
                const float w1 = __expf(e1);
                const float4 xa0 = *(const float4*)&P.xpad[s0 * 8];
                const float4 xb0 = *(const float4*)&P.xpad[s0 * 8 + 4];
                const float4 xa1 = *(const float4*)&P.xpad[s1 * 8];
                const float4 xb1 = *(const float4*)&P.xpad[s1 * 8 + 4];
                acc[0] += w0*xa0.x + w1*xa1.x;
                acc[1] += w0*xa0.y + w1*xa1.y;
                acc[2] += w0*xa0.z + w1*xa1.z;
                acc[3] += w0*xa0.w + w1*xa1.w;
                acc[4] += w0*xb0.x + w1*xb1.x;
                acc[5] += w0*xb0.y + w1*xb1.y;
                acc[6] += w0*xb0.z + w1*xb1.z;
                acc[7] += w0*xb0.w + w1*xb1.w;
            }
            // sum-reduce over the 16-lane head class
#pragma unroll
            for (int k = 0; k < 8; ++k) {
                acc[k] += __shfl_xor(acc[k], 1);
                acc[k] += __shfl_xor(acc[k], 2);
                acc[k] += __shfl_xor(acc[k], 4);
                acc[k] += __shfl_xor(acc[k], 8);
            }
            const float inv = 1.f / (acc[7] + 1e-16f);
            float sa[IN_DIM];
#pragma unroll
            for (int k = 0; k < IN_DIM; ++k) sa[k] = acc[k] * inv;

            // h1 channels cb+16j; 4 q-projections (als2, ald2, gu, gw)
            const int cb = head * 64 + slot;
            float ds = 0.f, dd = 0.f, du = 0.f, dw = 0.f;
#pragma unroll
            for (int jj = 0; jj < 4; ++jj) {
                const int c = cb + 16 * jj;
                float o = P.b1[c];
#pragma unroll
                for (int k = 0; k < IN_DIM; ++k)
                    o += sa[k] * P.W1[k * H1C1 + c];
                const float h1v = (o > 0.f) ? o : (__expf(o) - 1.f);
                ds += h1v * P.q[c];
                dd += h1v * P.q[256 + c];
                du += h1v * P.q[512 + c];
                dw += h1v * P.q[768 + c];
            }
#pragma unroll
            for (int sft = 32; sft; sft >>= 1) {
                ds += __shfl_xor(ds, sft);
                dd += __shfl_xor(dd, sft);
                du += __shfl_xor(du, sft);
                dw += __shfl_xor(dw, sft);
            }
            if (lane == 0) {
                float4 r = {ds, dd, du, dw};
                *(float4*)&P.n2[v * 4] = r;
            }
        }
    }
    gbar(bar, NBLK * 4);

    // ---------------- phase 5: agg2 (+ scorer projections, no-max) ------------
    for (int v = wgl; v < N_NODES; v += NWAVES) {
        const int start = P.off[v];
        const int dreal = P.deg[v];
        const int dtot  = dreal + 1;
        const float ad = P.n2[v * 4 + 1];

        float sw = 0.f, sgu = 0.f, sgw = 0.f;
        for (int b0 = 0; b0 < dtot; b0 += 64) {
            const int j = b0 + lane;
            const bool act = j < dtot;
            const int s = (j < dreal) ? P.csr[start + j] : v;
            const float4 r = *(const float4*)&P.n2[s * 4];
            float e = leaky(r.x + ad); if (!act) e = -1e30f;
            const float w = __expf(e);
            sw  += w;
            sgu += w * r.z;
            sgw += w * r.w;
        }
#pragma unroll
        for (int sft = 32; sft; sft >>= 1) {
            sw  += __shfl_xor(sw, sft);
            sgu += __shfl_xor(sgu, sft);
            sgw += __shfl_xor(sgw, sft);
        }
        if (lane == 0) {
            const float inv = 1.f / (sw + 1e-16f);
            P.uu[v] = sgu * inv + P.q[1024];
            P.ww[v] = sgw * inv + P.q[1025];
        }
    }
    gbar(bar, NBLK * 5);

    // ---------------- phase 6: score ------------------------------------------
    {
        const float b = P.bs[0];
        for (int p = tid; p < N_CAND; p += NT) {
            const int2 ab = ((const int2*)P.cand)[p];
            const float s = P.uu[ab.x] + P.ww[ab.y] + b;
            P.out[p] = 1.f / (1.f + __expf(-s));
        }
    }
}

// ---------------------------------------------------------------------------
extern "C" void kernel_launch(void* const* d_in, const int* in_sizes, int n_in,
                              void* d_out, int out_size, void* d_ws, size_t ws_size,
                              hipStream_t stream) {
    Params P;
    P.x      = (const float*)d_in[0];
    P.ei     = (const int*)  d_in[1];
    P.cand   = (const int*)  d_in[2];
    P.W1     = (const float*)d_in[3];
    P.a_src1 = (const float*)d_in[4];
    P.a_dst1 = (const float*)d_in[5];
    P.b1     = (const float*)d_in[6];
    P.W2     = (const float*)d_in[7];
    P.a_src2 = (const float*)d_in[8];
    P.a_dst2 = (const float*)d_in[9];
    P.b2     = (const float*)d_in[10];
    P.Ws     = (const float*)d_in[11];
    P.bs     = (const float*)d_in[12];
    P.out    = (float*)d_out;

    // workspace carve-up (4B elements)
    float* w = (float*)d_ws;
    P.xpad = w;                       w += (size_t)N_NODES * 8;
    P.n2   = w;                       w += (size_t)N_NODES * 4;
    P.als1 = w;                       w += (size_t)N_NODES * 4;
    P.ald1 = w;                       w += (size_t)N_NODES * 4;
    P.uu   = w;                       w += N_NODES;
    P.ww   = w;                       w += N_NODES;
    P.q    = w;                       w += 1028;
    P.deg  = (int*)w;                 // N_NODES + 2 (scan base, barrier counter)
    P.off  = P.deg + (N_NODES + 2);
    P.cur  = P.off + N_NODES;
    P.csr  = P.cur + N_NODES;         // N_EDGES (real edges; self-loops implicit)

    // zero degrees + scan base + barrier counter
    (void)hipMemsetAsync(P.deg, 0, (N_NODES + 2) * sizeof(int), stream);

    fused_kernel<<<NBLK, NTHR, 0, stream>>>(P);
}